// Round 3
// baseline (150.770 us; speedup 1.0000x reference)
//
#include <hip/hip_runtime.h>
#include <hip/hip_bf16.h>

// Problem constants (B,H,W,C = 32,32,32,256 -> l = 1024)
#define BATCH 32
#define L 1024
#define CD 256
#define BM 128         // pred rows per block
#define BN 128         // query cols per block
#define BK 64          // K per step (4 steps, all LDS-resident)
#define NRT (L / BM)   // 8 row tiles
#define NCT (L / BN)   // 8 col tiles
#define TILE_E 8192    // bf16 elements per 128x64 tile (16 KB)

typedef __bf16 bf16x8 __attribute__((ext_vector_type(8)));
typedef float  f32x4  __attribute__((ext_vector_type(4)));
typedef unsigned long long u64;

__device__ __forceinline__ unsigned int enc_f32(float f) {
    unsigned int u = __float_as_uint(f);
    return ((int)u < 0) ? ~u : (u | 0x80000000u);
}
__device__ __forceinline__ float dec_f32(unsigned int u) {
    u = (u & 0x80000000u) ? (u & 0x7FFFFFFFu) : ~u;
    return __uint_as_float(u);
}
__device__ __forceinline__ u64 pmax(u64 a, u64 b) { return a > b ? a : b; }

// async global->LDS, 16B per lane. LDS dest is wave-uniform base + lane*16
// (our dest is sX[s] + tid*16: linear per wave -> HW-compatible).
__device__ __forceinline__ void gl_lds16(const __bf16* g, __bf16* l) {
    __builtin_amdgcn_global_load_lds(
        (const __attribute__((address_space(1))) unsigned int*)g,
        (__attribute__((address_space(3))) unsigned int*)l, 16, 0, 0);
}

// Kernel 0: fp32 -> bf16 convert into the PRE-SWIZZLED tiled layout that is
// byte-identical to the LDS image kernel 1 wants:
//   dst[b][panel(8)][step(4)][row(128)][imgcol(64)]  (16 KB per tile)
// where imgcol slot s (8 bf16 each) holds input k-slot (s ^ (row&7)) of
// k-range [step*64, step*64+64). gload_lds then copies tiles LINEARLY and the
// existing swizzled fragment reads land on the right data (rule #21: swizzle
// on source + read, linear LDS dest).
// 2M threads, 1 thread = one 16B output unit (reads 32B fp32, writes 16B).
__global__ __launch_bounds__(256) void convert_kernel(
    const float* __restrict__ qg,   // feats1 [B][L][CD] (queries)
    const float* __restrict__ pg,   // feats2 [B][L][CD] (preds)
    __bf16* __restrict__ qsw,       // [B][8][4][128][64] swizzled bf16
    __bf16* __restrict__ psw)       // [B][8][4][128][64] swizzled bf16
{
    const unsigned int t = blockIdx.x * 256 + threadIdx.x;   // 0..2M-1
    const unsigned int v = t & ((1u << 20) - 1);
    const bool isQ = (t >> 20) != 0;                         // wave-uniform
    const float* src_base = isQ ? qg : pg;
    __bf16*      dst_base = isQ ? qsw : psw;

    const int s    = v & 7;                 // 16B output slot in row
    const int row  = (v >> 3) & 127;
    const int step = (v >> 10) & 3;
    const int pan  = (v >> 12) & 7;
    const int b    = v >> 15;

    const float* src = src_base
        + ((size_t)b * L + pan * 128 + row) * CD
        + step * 64 + ((s ^ (row & 7)) * 8);
    const float4 f0 = *(const float4*)src;
    const float4 f1 = *(const float4*)(src + 4);
    bf16x8 o;
    o[0] = (__bf16)f0.x; o[1] = (__bf16)f0.y; o[2] = (__bf16)f0.z; o[3] = (__bf16)f0.w;
    o[4] = (__bf16)f1.x; o[5] = (__bf16)f1.y; o[6] = (__bf16)f1.z; o[7] = (__bf16)f1.w;
    *(bf16x8*)&dst_base[(size_t)v * 8] = o;
}

// Kernel 1: one block = one 128x128 output tile of M[b] = P[rows] . Q[cols]^T.
// 512 threads = 8 waves (4 row x 2 col), wave tile 32x64 (acc 2x4).
// ALL K (4 tiles x 2 matrices = 128 KB) lives in LDS simultaneously: prologue
// issues 16 gload_lds per thread, loop is just counted-vmcnt + barrier + MFMA.
// No ds_write, no cvt, no staging VALU, no buffer rewrite hazards.
__global__ __launch_bounds__(512) void mm_argmax_kernel(
    const __bf16* __restrict__ qsw,  // queries, swizzled tiles
    const __bf16* __restrict__ psw,  // preds, swizzled tiles
    u64* __restrict__ colpart,       // [B][NRT][L] (enc(val)<<32)|~a
    u64* __restrict__ rowpart)       // [B][NCT][L] (enc(val)<<32)|~j
{
    __shared__ __bf16 sA[4][TILE_E];          // 64 KB
    __shared__ __bf16 sB[4][TILE_E];          // 64 KB
    __shared__ u64 sRow[2][BM];               // 2 KB
    __shared__ u64 sCol[4][BN];               // 4 KB

    const int tid = threadIdx.x;
    const int bid = blockIdx.x;
    // bid = tile*32 + b: XCD = bid%8 = b%8 -> batch sticks to one XCD; its
    // bf16 working set (P+Q = 1 MB x 4 batches/XCD) fits the 4 MB L2.
    const int b    = bid & 31;
    const int tile = bid >> 5;
    const int rt   = tile >> 3;
    const int ct   = tile & 7;
    const int row0 = rt * BM;
    const int col0 = ct * BN;

    const int lane = tid & 63;
    const int w    = tid >> 6;
    const int wm   = w >> 1;      // 0..3: wave rows wm*32
    const int wn   = w & 1;       // 0..1: wave cols wn*64
    const int quad = lane >> 4;
    const int l16  = lane & 15;

    const __bf16* pa = psw + (size_t)(b * 8 + rt) * 4 * TILE_E;
    const __bf16* pb = qsw + (size_t)(b * 8 + ct) * 4 * TILE_E;

    // ---- prologue: issue ALL 16 direct-to-LDS loads (4 per step) ----
    // issue order is step-major so vmcnt(16-4*(s+1)) gates step s.
    #pragma unroll
    for (int s = 0; s < 4; ++s) {
        gl_lds16(pa + s * TILE_E +        tid * 8, &sA[s][tid * 8]);
        gl_lds16(pa + s * TILE_E + 4096 + tid * 8, &sA[s][4096 + tid * 8]);
        gl_lds16(pb + s * TILE_E +        tid * 8, &sB[s][tid * 8]);
        gl_lds16(pb + s * TILE_E + 4096 + tid * 8, &sB[s][4096 + tid * 8]);
    }

    f32x4 acc[2][4];
    #pragma unroll
    for (int tm = 0; tm < 2; ++tm)
        #pragma unroll
        for (int tn = 0; tn < 4; ++tn) acc[tm][tn] = (f32x4){0.f, 0.f, 0.f, 0.f};

    // each wave waits its OWN 4 loads for step s; barrier => all waves' done.
    #define STEP_SYNC(N)                                           \
        asm volatile("s_waitcnt vmcnt(" #N ")" ::: "memory");      \
        __builtin_amdgcn_s_barrier();                              \
        __builtin_amdgcn_sched_barrier(0);

    #define COMPUTE(s)                                                         \
        __builtin_amdgcn_s_setprio(1);                                         \
        _Pragma("unroll")                                                      \
        for (int kk = 0; kk < 2; ++kk) {                                       \
            const int sw = ((kk * 4 + quad) ^ (l16 & 7)) << 3;                 \
            bf16x8 a0 = *(const bf16x8*)&sA[s][(wm * 32      + l16) * BK + sw]; \
            bf16x8 a1 = *(const bf16x8*)&sA[s][(wm * 32 + 16 + l16) * BK + sw]; \
            bf16x8 b0 = *(const bf16x8*)&sB[s][(wn * 64      + l16) * BK + sw]; \
            bf16x8 b1 = *(const bf16x8*)&sB[s][(wn * 64 + 16 + l16) * BK + sw]; \
            bf16x8 b2 = *(const bf16x8*)&sB[s][(wn * 64 + 32 + l16) * BK + sw]; \
            bf16x8 b3 = *(const bf16x8*)&sB[s][(wn * 64 + 48 + l16) * BK + sw]; \
            acc[0][0] = __builtin_amdgcn_mfma_f32_16x16x32_bf16(a0, b0, acc[0][0], 0, 0, 0); \
            acc[0][1] = __builtin_amdgcn_mfma_f32_16x16x32_bf16(a0, b1, acc[0][1], 0, 0, 0); \
            acc[0][2] = __builtin_amdgcn_mfma_f32_16x16x32_bf16(a0, b2, acc[0][2], 0, 0, 0); \
            acc[0][3] = __builtin_amdgcn_mfma_f32_16x16x32_bf16(a0, b3, acc[0][3], 0, 0, 0); \
            acc[1][0] = __builtin_amdgcn_mfma_f32_16x16x32_bf16(a1, b0, acc[1][0], 0, 0, 0); \
            acc[1][1] = __builtin_amdgcn_mfma_f32_16x16x32_bf16(a1, b1, acc[1][1], 0, 0, 0); \
            acc[1][2] = __builtin_amdgcn_mfma_f32_16x16x32_bf16(a1, b2, acc[1][2], 0, 0, 0); \
            acc[1][3] = __builtin_amdgcn_mfma_f32_16x16x32_bf16(a1, b3, acc[1][3], 0, 0, 0); \
        }                                                                      \
        __builtin_amdgcn_s_setprio(0);

    STEP_SYNC(12) COMPUTE(0)
    STEP_SYNC(8)  COMPUTE(1)
    STEP_SYNC(4)  COMPUTE(2)
    STEP_SYNC(0)  COMPUTE(3)

    #undef STEP_SYNC
    #undef COMPUTE

    // ---- epilogue (once per block) ----
    // C/D layout (m89/m91): col = l16, row = quad*4 + r within each 16x16 frag.
    const int a_base = row0 + wm * 32 + quad * 4;  // + tm*16 + r
    const int j_base = col0 + wn * 64 + l16;       // + tn*16

    // column argmax over this block's 128 rows (ascending a => first-index ties)
    #pragma unroll
    for (int tn = 0; tn < 4; ++tn) {
        float cv = acc[0][tn][0];
        int   ca = a_base;
        #pragma unroll
        for (int tm = 0; tm < 2; ++tm)
            #pragma unroll
            for (int r = 0; r < 4; ++r) {
                if (tm == 0 && r == 0) continue;
                const float v = acc[tm][tn][r];
                const int   a = a_base + tm * 16 + r;
                if (v > cv) { cv = v; ca = a; }
            }
        u64 pk = ((u64)enc_f32(cv) << 32) | (unsigned int)(~(unsigned int)ca);
        pk = pmax(pk, __shfl_xor(pk, 16));   // combine across quads (rows)
        pk = pmax(pk, __shfl_xor(pk, 32));
        if (quad == 0) sCol[wm][wn * 64 + tn * 16 + l16] = pk;
    }

    // row argmax over this block's 128 cols (ascending j => first-index ties)
    #pragma unroll
    for (int tm = 0; tm < 2; ++tm)
        #pragma unroll
        for (int r = 0; r < 4; ++r) {
            float rv = acc[tm][0][r];
            int   rj = j_base;
            #pragma unroll
            for (int tn = 1; tn < 4; ++tn) {
                const float v = acc[tm][tn][r];
                if (v > rv) { rv = v; rj = j_base + tn * 16; }
            }
            u64 pk = ((u64)enc_f32(rv) << 32) | (unsigned int)(~(unsigned int)rj);
            pk = pmax(pk, __shfl_xor(pk, 1));  // combine across l16 (cols)
            pk = pmax(pk, __shfl_xor(pk, 2));
            pk = pmax(pk, __shfl_xor(pk, 4));
            pk = pmax(pk, __shfl_xor(pk, 8));
            if (l16 == 0) sRow[wn][wm * 32 + tm * 16 + quad * 4 + r] = pk;
        }

    __syncthreads();
    if (tid < BN) {
        u64 c = pmax(pmax(sCol[0][tid], sCol[1][tid]),
                     pmax(sCol[2][tid], sCol[3][tid]));
        colpart[((size_t)b * NRT + rt) * L + col0 + tid] = c;
        u64 rr = pmax(sRow[0][tid], sRow[1][tid]);
        rowpart[((size_t)b * NCT + ct) * L + row0 + tid] = rr;
    }
}

// Kernel 2: merged reduce + mutual-NN + mean. One block per batch, 1024 thr.
__global__ __launch_bounds__(1024) void finalize_kernel(
    const u64* __restrict__ colpart,  // [B][NRT][L]
    const u64* __restrict__ rowpart,  // [B][NCT][L]
    float* __restrict__ out)
{
    __shared__ int sMax2[L];
    __shared__ float sSum[16];
    __shared__ int sCnt[16];
    const int b = blockIdx.x;
    const int j = threadIdx.x;        // 0..1023

    u64 rb = 0ull;
    #pragma unroll
    for (int ct = 0; ct < NCT; ++ct)
        rb = pmax(rb, rowpart[((size_t)b * NCT + ct) * L + j]);
    sMax2[j] = (int)(~(unsigned int)rb) & (L - 1);

    u64 cb = 0ull;
    #pragma unroll
    for (int rt = 0; rt < NRT; ++rt)
        cb = pmax(cb, colpart[((size_t)b * NRT + rt) * L + j]);
    __syncthreads();

    const int a = (int)(~(unsigned int)cb) & (L - 1);      // max1[j]
    const float val = dec_f32((unsigned int)(cb >> 32));   // sims[j]
    const bool mut = (sMax2[a] == j);                      // mutual NN
    float sum = mut ? val : 0.f;
    int   cnt = mut ? 1 : 0;

    #pragma unroll
    for (int o = 32; o >= 1; o >>= 1) {
        sum += __shfl_down(sum, o);
        cnt += __shfl_down(cnt, o);
    }
    if ((j & 63) == 0) { sSum[j >> 6] = sum; sCnt[j >> 6] = cnt; }
    __syncthreads();
    if (j == 0) {
        float S = 0.f;
        int   C = 0;
        #pragma unroll
        for (int i = 0; i < 16; ++i) { S += sSum[i]; C += sCnt[i]; }
        out[b] = S / fmaxf((float)C, 1.0f);
    }
}

extern "C" void kernel_launch(void* const* d_in, const int* in_sizes, int n_in,
                              void* d_out, int out_size, void* d_ws, size_t ws_size,
                              hipStream_t stream) {
    const float* q = (const float*)d_in[0];   // feats1 (queries)
    const float* p = (const float*)d_in[1];   // feats2 (preds)
    float* out = (float*)d_out;

    // ws layout: colpart [32][8][1024] u64 (2 MiB) | rowpart (2 MiB) |
    // psw bf16 (16 MiB) | qsw bf16 (16 MiB). Total 36 MiB.
    // Every slot written before read -> no init needed.
    u64* colpart = (u64*)d_ws;
    u64* rowpart = colpart + (size_t)BATCH * NRT * L;
    __bf16* psw = (__bf16*)(rowpart + (size_t)BATCH * NCT * L);
    __bf16* qsw = psw + (size_t)BATCH * 8 * 4 * TILE_E;

    convert_kernel<<<8192, 256, 0, stream>>>(q, p, qsw, psw);
    mm_argmax_kernel<<<BATCH * NRT * NCT, 512, 0, stream>>>(qsw, psw, colpart, rowpart);
    finalize_kernel<<<BATCH, 1024, 0, stream>>>(colpart, rowpart, out);
}

// Round 4
// 141.004 us; speedup vs baseline: 1.0693x; 1.0693x over previous
//
#include <hip/hip_runtime.h>
#include <hip/hip_bf16.h>

// Problem constants (B,H,W,C = 32,32,32,256 -> l = 1024)
#define BATCH 32
#define L 1024
#define CD 256
#define NRT 8          // row panels of 128 (A side, preds)
#define NCT 16         // col tiles of 64 (B side, queries)
#define PAN_A 32768    // bf16 elements per A panel (128 x 256)
#define TILE_B 16384   // bf16 elements per B tile  (64 x 256)

typedef __bf16 bf16x8 __attribute__((ext_vector_type(8)));
typedef float  f32x4  __attribute__((ext_vector_type(4)));
typedef unsigned long long u64;

__device__ __forceinline__ unsigned int enc_f32(float f) {
    unsigned int u = __float_as_uint(f);
    return ((int)u < 0) ? ~u : (u | 0x80000000u);
}
__device__ __forceinline__ float dec_f32(unsigned int u) {
    u = (u & 0x80000000u) ? (u & 0x7FFFFFFFu) : ~u;
    return __uint_as_float(u);
}
__device__ __forceinline__ u64 pmax(u64 a, u64 b) { return a > b ? a : b; }

// async global->LDS, 16B/lane; LDS dest = wave-uniform base + lane*16.
__device__ __forceinline__ void gl_lds16(const __bf16* g, __bf16* l) {
    __builtin_amdgcn_global_load_lds(
        (const __attribute__((address_space(1))) unsigned int*)g,
        (__attribute__((address_space(3))) unsigned int*)l, 16, 0, 0);
}

// Kernel 0: fp32 -> bf16 convert into PRE-SWIZZLED tiled layouts (the exact
// LDS images kernel 1 wants; rule #21: swizzle source + read, linear LDS dest):
//   psw: [b][rt(8)][step(4)][row(128)][64k]   (A panels, 16 KB x4 per panel)
//   qsw: [b][ct(16)][step(4)][row(64)][64k]   (B tiles, 32 KB per tile)
// 16B slot s of a row holds input k-slot (s ^ (row&7)) of that step's k-range.
__global__ __launch_bounds__(256) void convert_kernel(
    const float* __restrict__ qg,   // feats1 [B][L][CD] (queries)
    const float* __restrict__ pg,   // feats2 [B][L][CD] (preds)
    __bf16* __restrict__ qsw,
    __bf16* __restrict__ psw)
{
    const unsigned int t = blockIdx.x * 256 + threadIdx.x;   // 0..2M-1
    const unsigned int v = t & ((1u << 20) - 1);
    const bool isQ = (t >> 20) != 0;                         // wave-uniform

    const float* src;
    __bf16* dst;
    if (isQ) {
        const int s    = v & 7;
        const int row  = (v >> 3) & 63;
        const int step = (v >> 9) & 3;
        const int ct   = (v >> 11) & 15;
        const int b    = v >> 15;
        src = qg + ((size_t)(b * L + ct * 64 + row)) * CD
                 + step * 64 + ((s ^ (row & 7)) * 8);
        dst = qsw + (size_t)v * 8;
    } else {
        const int s    = v & 7;
        const int row  = (v >> 3) & 127;
        const int step = (v >> 10) & 3;
        const int pan  = (v >> 12) & 7;
        const int b    = v >> 15;
        src = pg + ((size_t)(b * L + pan * 128 + row)) * CD
                 + step * 64 + ((s ^ (row & 7)) * 8);
        dst = psw + (size_t)v * 8;
    }
    const float4 f0 = *(const float4*)src;
    const float4 f1 = *(const float4*)(src + 4);
    bf16x8 o;
    o[0] = (__bf16)f0.x; o[1] = (__bf16)f0.y; o[2] = (__bf16)f0.z; o[3] = (__bf16)f0.w;
    o[4] = (__bf16)f1.x; o[5] = (__bf16)f1.y; o[6] = (__bf16)f1.z; o[7] = (__bf16)f1.w;
    *(bf16x8*)&dst[0] = o;
}

// Kernel 1: 256 blocks = 1/CU, single round. Block (b, rt) owns 128 pred rows
// x ALL 1024 query cols. A panel (64 KB, full K) resident; B tiles (32 KB)
// double-buffered via gload_lds with counted vmcnt(6) (never drained).
// 8 waves = 4(row) x 2(col); wave tile 32x32, acc 2x2.
// Row argmax (max2) completes in-block; col partials [rt*4+wm] go to global.
__global__ __launch_bounds__(512, 2) void mm_argmax_kernel(
    const __bf16* __restrict__ qsw,
    const __bf16* __restrict__ psw,
    u64* __restrict__ colpart,   // [B][32][L] (enc(val)<<32)|~a
    int* __restrict__ max2)      // [B][L]
{
    __shared__ __bf16 sA[4 * 8192];      // 64 KB: [step][row128][64]
    __shared__ __bf16 sB[2][4 * 4096];   // 64 KB: [buf][step][row64][64]
    __shared__ u64 sRow[2][128];         // 2 KB

    const int tid = threadIdx.x;
    const int bid = blockIdx.x;
    // bid = rt*32 + b -> XCD = b%8 (sticky): batch panels stay L2-local.
    const int b  = bid & 31;
    const int rt = bid >> 5;

    const int lane = tid & 63;
    const int w    = tid >> 6;
    const int wm   = w >> 1;      // 0..3: rows wm*32
    const int wn   = w & 1;       // 0..1: cols wn*32 within 64-col tile
    const int quad = lane >> 4;
    const int l16  = lane & 15;

    const __bf16* pa  = psw + (size_t)(b * NRT + rt) * PAN_A;
    const __bf16* pbb = qsw + (size_t)b * NCT * TILE_B;

    // ---- prologue: A panel (8 chunks) + B tiles 0 and 1 (4 chunks each) ----
    #pragma unroll
    for (int c = 0; c < 8; ++c)
        gl_lds16(pa + c * 4096 + tid * 8, &sA[c * 4096 + tid * 8]);
    #pragma unroll
    for (int c = 0; c < 4; ++c)
        gl_lds16(pbb + c * 4096 + tid * 8, &sB[0][c * 4096 + tid * 8]);
    #pragma unroll
    for (int c = 0; c < 4; ++c)
        gl_lds16(pbb + TILE_B + c * 4096 + tid * 8, &sB[1][c * 4096 + tid * 8]);

    f32x4 acc[2][2];
    float rowv[2][4];
    int   rowj[2][4];
    #pragma unroll
    for (int tm = 0; tm < 2; ++tm)
        #pragma unroll
        for (int r = 0; r < 4; ++r) { rowv[tm][r] = -1e30f; rowj[tm][r] = 0; }

    // A + B0 ready (B1's 4 loads still in flight)
    asm volatile("s_waitcnt vmcnt(4)" ::: "memory");
    __builtin_amdgcn_s_barrier();
    __builtin_amdgcn_sched_barrier(0);

    const size_t colbase = ((size_t)(b * NRT + rt) * 4 + wm) * L;
    const int a0q = rt * 128 + wm * 32 + quad * 4;   // + tm*16 + r

    for (int t = 0; t < NCT; ++t) {
        const __bf16* sBb = sB[t & 1];
        #pragma unroll
        for (int tm = 0; tm < 2; ++tm)
            #pragma unroll
            for (int tn = 0; tn < 2; ++tn) acc[tm][tn] = (f32x4){0.f, 0.f, 0.f, 0.f};

        __builtin_amdgcn_s_setprio(1);
        #pragma unroll
        for (int step = 0; step < 4; ++step) {
            #pragma unroll
            for (int kk = 0; kk < 2; ++kk) {
                const int sw = ((kk * 4 + quad) ^ (l16 & 7)) << 3;
                bf16x8 a0 = *(const bf16x8*)&sA [step * 8192 + (wm * 32      + l16) * 64 + sw];
                bf16x8 a1 = *(const bf16x8*)&sA [step * 8192 + (wm * 32 + 16 + l16) * 64 + sw];
                bf16x8 b0 = *(const bf16x8*)&sBb[step * 4096 + (wn * 32      + l16) * 64 + sw];
                bf16x8 b1 = *(const bf16x8*)&sBb[step * 4096 + (wn * 32 + 16 + l16) * 64 + sw];
                acc[0][0] = __builtin_amdgcn_mfma_f32_16x16x32_bf16(a0, b0, acc[0][0], 0, 0, 0);
                acc[0][1] = __builtin_amdgcn_mfma_f32_16x16x32_bf16(a0, b1, acc[0][1], 0, 0, 0);
                acc[1][0] = __builtin_amdgcn_mfma_f32_16x16x32_bf16(a1, b0, acc[1][0], 0, 0, 0);
                acc[1][1] = __builtin_amdgcn_mfma_f32_16x16x32_bf16(a1, b1, acc[1][1], 0, 0, 0);
            }
        }
        __builtin_amdgcn_s_setprio(0);

        // row running argmax (j ascends with t/tn; strict > keeps first index)
        const int jb = t * 64 + wn * 32 + l16;
        #pragma unroll
        for (int tm = 0; tm < 2; ++tm)
            #pragma unroll
            for (int r = 0; r < 4; ++r) {
                const float v0 = acc[tm][0][r], v1 = acc[tm][1][r];
                if (v0 > rowv[tm][r]) { rowv[tm][r] = v0; rowj[tm][r] = jb; }
                if (v1 > rowv[tm][r]) { rowv[tm][r] = v1; rowj[tm][r] = jb + 16; }
            }

        // column argmax over this wave's 32 rows (ascending a scan), combine
        // quads, store partial. 2 stores/wave/tile -> vmcnt accounting below.
        #pragma unroll
        for (int tn = 0; tn < 2; ++tn) {
            float cv = acc[0][tn][0];
            int   ca = a0q;
            #pragma unroll
            for (int r = 1; r < 4; ++r)
                if (acc[0][tn][r] > cv) { cv = acc[0][tn][r]; ca = a0q + r; }
            #pragma unroll
            for (int r = 0; r < 4; ++r)
                if (acc[1][tn][r] > cv) { cv = acc[1][tn][r]; ca = a0q + 16 + r; }
            u64 pk = ((u64)enc_f32(cv) << 32) | (unsigned int)(~(unsigned int)ca);
            pk = pmax(pk, __shfl_xor(pk, 16));
            pk = pmax(pk, __shfl_xor(pk, 32));
            if (quad == 0)
                colpart[colbase + t * 64 + wn * 32 + tn * 16 + l16] = pk;
        }

        __builtin_amdgcn_s_barrier();        // all readers done with sB[t&1]
        __builtin_amdgcn_sched_barrier(0);
        if (t + 2 < NCT) {
            #pragma unroll
            for (int c = 0; c < 4; ++c)
                gl_lds16(pbb + (size_t)(t + 2) * TILE_B + c * 4096 + tid * 8,
                         &sB[t & 1][c * 4096 + tid * 8]);
        }
        if (t < NCT - 1) {
            // gate B(t+1): newer ops in FIFO = 2 col stores + (4 loads if issued)
            if (t + 2 < NCT) { asm volatile("s_waitcnt vmcnt(6)" ::: "memory"); }
            else             { asm volatile("s_waitcnt vmcnt(2)" ::: "memory"); }
            __builtin_amdgcn_s_barrier();
            __builtin_amdgcn_sched_barrier(0);
        }
    }

    // ---- row argmax finish: reduce over l16 lanes, combine wn pair ----
    #pragma unroll
    for (int tm = 0; tm < 2; ++tm)
        #pragma unroll
        for (int r = 0; r < 4; ++r) {
            u64 pk = ((u64)enc_f32(rowv[tm][r]) << 32)
                   | (unsigned int)(~(unsigned int)rowj[tm][r]);
            pk = pmax(pk, __shfl_xor(pk, 1));
            pk = pmax(pk, __shfl_xor(pk, 2));
            pk = pmax(pk, __shfl_xor(pk, 4));
            pk = pmax(pk, __shfl_xor(pk, 8));
            if (l16 == 0) sRow[wn][wm * 32 + tm * 16 + quad * 4 + r] = pk;
        }
    __syncthreads();
    if (tid < 128) {
        const u64 m = pmax(sRow[0][tid], sRow[1][tid]);
        max2[(size_t)b * L + rt * 128 + tid] = (int)(~(unsigned int)m) & (L - 1);
    }
}

// Kernel 2: reduce col partials (32-deep) + mutual-NN + mean. 1 block/batch.
__global__ __launch_bounds__(1024) void finalize_kernel(
    const u64* __restrict__ colpart,  // [B][32][L]
    const int* __restrict__ max2,     // [B][L]
    float* __restrict__ out)
{
    __shared__ int sMax2[L];
    __shared__ float sSum[16];
    __shared__ int sCnt[16];
    const int b = blockIdx.x;
    const int j = threadIdx.x;        // 0..1023

    sMax2[j] = max2[(size_t)b * L + j];

    u64 cb = 0ull;
    #pragma unroll
    for (int k = 0; k < 32; ++k)
        cb = pmax(cb, colpart[((size_t)b * 32 + k) * L + j]);
    __syncthreads();

    const int a = (int)(~(unsigned int)cb) & (L - 1);      // max1[j]
    const float val = dec_f32((unsigned int)(cb >> 32));   // sims[j]
    const bool mut = (sMax2[a] == j);                      // mutual NN
    float sum = mut ? val : 0.f;
    int   cnt = mut ? 1 : 0;

    #pragma unroll
    for (int o = 32; o >= 1; o >>= 1) {
        sum += __shfl_down(sum, o);
        cnt += __shfl_down(cnt, o);
    }
    if ((j & 63) == 0) { sSum[j >> 6] = sum; sCnt[j >> 6] = cnt; }
    __syncthreads();
    if (j == 0) {
        float S = 0.f;
        int   C = 0;
        #pragma unroll
        for (int i = 0; i < 16; ++i) { S += sSum[i]; C += sCnt[i]; }
        out[b] = S / fmaxf((float)C, 1.0f);
    }
}

extern "C" void kernel_launch(void* const* d_in, const int* in_sizes, int n_in,
                              void* d_out, int out_size, void* d_ws, size_t ws_size,
                              hipStream_t stream) {
    const float* q = (const float*)d_in[0];   // feats1 (queries)
    const float* p = (const float*)d_in[1];   // feats2 (preds)
    float* out = (float*)d_out;

    // ws layout: colpart [32][32][1024] u64 (8 MiB) | max2 [32][1024] int
    // (128 KiB) | psw bf16 (16 MiB) | qsw bf16 (16 MiB). ~40 MiB total.
    // Every slot written before read -> no init needed.
    u64* colpart = (u64*)d_ws;
    int* max2 = (int*)(colpart + (size_t)BATCH * 32 * L);
    __bf16* psw = (__bf16*)((char*)d_ws + 8 * 1024 * 1024 + 512 * 1024);
    __bf16* qsw = psw + (size_t)BATCH * NRT * PAN_A;

    convert_kernel<<<8192, 256, 0, stream>>>(q, p, qsw, psw);
    mm_argmax_kernel<<<BATCH * NRT, 512, 0, stream>>>(qsw, psw, colpart, max2);
    finalize_kernel<<<BATCH, 1024, 0, stream>>>(colpart, max2, out);
}